// Round 4
// baseline (1213.497 us; speedup 1.0000x reference)
//
#include <hip/hip_runtime.h>
#include <hip/hip_bf16.h>
#include <stdint.h>

#define E_ 4
#define T_ 4096
#define D_ 2048
#define H_ 8192

typedef __attribute__((ext_vector_type(8))) short bf16x8;
typedef __attribute__((ext_vector_type(4))) float f32x4;

// round-to-nearest-even f32 -> bf16 bit pattern
__device__ __forceinline__ unsigned short f2bf(float f) {
    unsigned int u = __float_as_uint(f);
    u = u + 0x7fffu + ((u >> 16) & 1u);
    return (unsigned short)(u >> 16);
}

// async global->LDS, 16B per lane. LDS dest is wave-uniform base; HW adds lane*16.
__device__ __forceinline__ void async16(const unsigned short* g, unsigned short* l) {
    auto gp = (const __attribute__((address_space(1))) unsigned int*)g;
    auto lp = (__attribute__((address_space(3))) unsigned int*)l;
    __builtin_amdgcn_global_load_lds(gp, lp, 16 /*bytes*/, 0 /*offset*/, 0 /*aux*/);
}

__device__ __forceinline__ f32x4 mfma16(bf16x8 a, bf16x8 b, f32x4 c) {
    return __builtin_amdgcn_mfma_f32_16x16x32_bf16(a, b, c, 0, 0, 0);
}

// ---------------- x: f32 -> bf16 (vectorized) ----------------
__global__ void cvt_x_kernel(const float4* __restrict__ in, uint2* __restrict__ out, long n4) {
    long i = (long)blockIdx.x * blockDim.x + threadIdx.x;
    long stride = (long)gridDim.x * blockDim.x;
    for (; i < n4; i += stride) {
        float4 v = in[i];
        uint2 o;
        o.x = (unsigned)f2bf(v.x) | ((unsigned)f2bf(v.y) << 16);
        o.y = (unsigned)f2bf(v.z) | ((unsigned)f2bf(v.w) << 16);
        out[i] = o;
    }
}

// ---------------- W (R x C, f32, row-major) -> Wt (C x R, bf16) per expert ----------------
__global__ void transpose_cvt_kernel(const float* __restrict__ W, unsigned short* __restrict__ Wt,
                                     int R, int C) {
    __shared__ float tile[64][65];
    const float* Wp = W + (size_t)blockIdx.z * R * C;
    unsigned short* Wtp = Wt + (size_t)blockIdx.z * R * C;
    const int c0 = blockIdx.x * 64, r0 = blockIdx.y * 64;
    const int tc = threadIdx.x & 63;
    const int tr = threadIdx.x >> 6; // 0..3
#pragma unroll
    for (int i = 0; i < 16; ++i) {
        int r = tr * 16 + i;
        tile[r][tc] = Wp[(size_t)(r0 + r) * C + c0 + tc];
    }
    __syncthreads();
#pragma unroll
    for (int i = 0; i < 16; ++i) {
        int r = tr * 16 + i;
        Wtp[(size_t)(c0 + r) * R + r0 + tc] = f2bf(tile[tc][r]);
    }
}

// ---------------- 256x256 8-phase GEMM: C[M][N] = A[M][K] * Bt[N][K]^T (+bias) ----------------
// 8 waves (2M x 4N), per-wave 128x64 output = acc[8][4] of 16x16 frags. BK=64.
// LDS: 2 dbuf x {A,B} x 2 halves x [128][64] bf16 = 128 KiB. XOR swizzle kel ^= (row&7)<<3
// on both the pre-swizzled global_load_lds source and the ds_read address (verified conflict-free).
// m201-faithful 4-phase/K-tile schedule (reads spread 12/4/8/0, stage 1 half-tile per phase,
// counted vmcnt(4) once per K-tile at P4):
//   P1: rd b-lo(4)+a-lo(8); stg A0(t+1); bar; lgkm0; 16 MFMA Q11; bar
//   P2: rd b-hi(4);         stg A1(t+1); bar; lgkm0; 16 MFMA Q12; bar
//   P3: rd a-hi(8,reuse);   stg B0(t+2); bar; lgkm0; 16 MFMA Q21; bar
//   P4:                     stg B1(t+2);             16 MFMA Q22; vmcnt(4); bar
// Region-death: each phase's closing barrier is after every wave's lgkmcnt(0)+MFMA, so that
// phase's reads are globally landed. B(s) dead after P2-close (staged P3/P4); A(s) dead after
// P3-close (staged P1/P2 of next iter). vmcnt(4) = the 4 B(t+2) ops issued this K-tile.
template <int K, int OUT_MODE>
__global__ __launch_bounds__(512, 2) void gemm256_kernel(
    const unsigned short* __restrict__ A,   // [E][M][K]
    const unsigned short* __restrict__ Bt,  // [E][N][K]
    const float* __restrict__ bias,         // [E][N]
    void* __restrict__ Cout,                // [E][M][N]
    int M, int N)
{
    constexpr int BK = 64;
    constexpr int NT = K / BK;
    __shared__ __align__(16) unsigned short L[2][2][2][128][64]; // [dbuf][A/B][half][row][kel]

    // ---- XCD-aware swizzle of the full linearized grid (nwg % 8 == 0 for all our grids)
    const int nx = gridDim.x, ny = gridDim.y;
    const int nwg = nx * ny * gridDim.z;
    const int w = (blockIdx.z * ny + blockIdx.y) * nx + blockIdx.x;
    const int cpx = nwg >> 3;
    const int lid = (w & 7) * cpx + (w >> 3);
    const int e  = lid / (nx * ny);
    const int r2 = lid % (nx * ny);
    const int by = r2 / nx, bx = r2 % nx;

    const unsigned short* Ae = A + (size_t)e * M * K;
    const unsigned short* Be = Bt + (size_t)e * N * K;
    const int bm0 = by * 256;
    const int bn0 = bx * 256;

    const int tid = threadIdx.x;
    const int lane = tid & 63;
    const int wid = tid >> 6;     // 0..7
    const int wr = wid >> 2;      // 0..1 (M half)
    const int wc = wid & 3;       // 0..3 (N quarter)

    // staging geometry: per call i in 0..1, rows wid*16 + i*8 + (lane>>3)
    const int srow = wid * 16 + (lane >> 3);
    const int skel = 8 * ((lane & 7) ^ (lane >> 3)); // pre-swizzled global k offset

    // fragment-read geometry
    const int fr = lane & 15;
    const int kq = lane >> 4;          // 0..3
    const int ksw = (lane & 7) << 3;   // read-side swizzle (elements)
    const int bh = wc >> 1;            // B half this wave reads
    const int brb = (wc & 1) * 64;     // B row base within half

    f32x4 acc[8][4] = {};

    auto stageA = [&](int t, int h) {
        const int k0 = t * BK;
        const int s = t & 1;
#pragma unroll
        for (int i = 0; i < 2; ++i) {
            async16(Ae + (size_t)(bm0 + h * 128 + srow + i * 8) * K + k0 + skel,
                    &L[s][0][h][wid * 16 + i * 8][0]);
        }
    };
    auto stageB = [&](int t, int h) {
        const int k0 = t * BK;
        const int s = t & 1;
#pragma unroll
        for (int i = 0; i < 2; ++i) {
            async16(Be + (size_t)(bn0 + h * 128 + srow + i * 8) * K + k0 + skel,
                    &L[s][1][h][wid * 16 + i * 8][0]);
        }
    };

    // ---- prologue: tile 0 complete (8 ops) + B halves of tile 1 (4 ops)
    stageB(0, 0); stageB(0, 1); stageA(0, 0); stageA(0, 1);
    stageB(1, 0); stageB(1, 1);
    asm volatile("s_waitcnt vmcnt(4)" ::: "memory"); // tile 0 landed; tile-1 B may be in flight
    __builtin_amdgcn_s_barrier();

    bf16x8 a[4][2], b[4][2];

    for (int t = 0; t < NT; ++t) {
        const int s = t & 1;

        // ================ P1: rd b-lo + a-lo; stage A0(t+1) ================
#pragma unroll
        for (int n = 0; n < 2; ++n)
#pragma unroll
            for (int kk = 0; kk < 2; ++kk)
                b[n][kk] = *(const bf16x8*)&L[s][1][bh][brb + n * 16 + fr][(kk * 32 + kq * 8) ^ ksw];
#pragma unroll
        for (int m = 0; m < 4; ++m)
#pragma unroll
            for (int kk = 0; kk < 2; ++kk)
                a[m][kk] = *(const bf16x8*)&L[s][0][wr][m * 16 + fr][(kk * 32 + kq * 8) ^ ksw];
        if (t + 1 < NT) stageA(t + 1, 0);
        __builtin_amdgcn_sched_barrier(0);
        __builtin_amdgcn_s_barrier();
        asm volatile("s_waitcnt lgkmcnt(0)" ::: "memory");
        __builtin_amdgcn_sched_barrier(0);
        __builtin_amdgcn_s_setprio(1);
#pragma unroll
        for (int m = 0; m < 4; ++m)
#pragma unroll
            for (int n = 0; n < 2; ++n)
#pragma unroll
                for (int kk = 0; kk < 2; ++kk)
                    acc[m][n] = mfma16(a[m][kk], b[n][kk], acc[m][n]);
        __builtin_amdgcn_s_setprio(0);
        __builtin_amdgcn_s_barrier();

        // ================ P2: rd b-hi; stage A1(t+1) ================
#pragma unroll
        for (int n = 2; n < 4; ++n)
#pragma unroll
            for (int kk = 0; kk < 2; ++kk)
                b[n][kk] = *(const bf16x8*)&L[s][1][bh][brb + n * 16 + fr][(kk * 32 + kq * 8) ^ ksw];
        if (t + 1 < NT) stageA(t + 1, 1);
        __builtin_amdgcn_sched_barrier(0);
        __builtin_amdgcn_s_barrier();
        asm volatile("s_waitcnt lgkmcnt(0)" ::: "memory");
        __builtin_amdgcn_sched_barrier(0);
        __builtin_amdgcn_s_setprio(1);
#pragma unroll
        for (int m = 0; m < 4; ++m)
#pragma unroll
            for (int n = 2; n < 4; ++n)
#pragma unroll
                for (int kk = 0; kk < 2; ++kk)
                    acc[m][n] = mfma16(a[m][kk], b[n][kk], acc[m][n]);
        __builtin_amdgcn_s_setprio(0);
        __builtin_amdgcn_s_barrier();

        // ================ P3: rd a-hi (reuse a regs); stage B0(t+2) ================
#pragma unroll
        for (int m = 0; m < 4; ++m)
#pragma unroll
            for (int kk = 0; kk < 2; ++kk)
                a[m][kk] = *(const bf16x8*)&L[s][0][wr][(m + 4) * 16 + fr][(kk * 32 + kq * 8) ^ ksw];
        if (t + 2 < NT) stageB(t + 2, 0);
        __builtin_amdgcn_sched_barrier(0);
        __builtin_amdgcn_s_barrier();
        asm volatile("s_waitcnt lgkmcnt(0)" ::: "memory");
        __builtin_amdgcn_sched_barrier(0);
        __builtin_amdgcn_s_setprio(1);
#pragma unroll
        for (int m = 0; m < 4; ++m)
#pragma unroll
            for (int n = 0; n < 2; ++n)
#pragma unroll
                for (int kk = 0; kk < 2; ++kk)
                    acc[m + 4][n] = mfma16(a[m][kk], b[n][kk], acc[m + 4][n]);
        __builtin_amdgcn_s_setprio(0);
        __builtin_amdgcn_s_barrier();

        // ================ P4: stage B1(t+2); MFMA Q22; counted vmcnt ================
        if (t + 2 < NT) stageB(t + 2, 1);
        __builtin_amdgcn_sched_barrier(0);
        __builtin_amdgcn_s_setprio(1);
#pragma unroll
        for (int m = 0; m < 4; ++m)
#pragma unroll
            for (int n = 2; n < 4; ++n)
#pragma unroll
                for (int kk = 0; kk < 2; ++kk)
                    acc[m + 4][n] = mfma16(a[m][kk], b[n][kk], acc[m + 4][n]);
        __builtin_amdgcn_s_setprio(0);
        if (t + 2 < NT) {
            asm volatile("s_waitcnt vmcnt(4)" ::: "memory"); // tile t+1 fully landed; t+2's 4 B-ops in flight
        } else {
            asm volatile("s_waitcnt vmcnt(0)" ::: "memory"); // tail drain
        }
        __builtin_amdgcn_sched_barrier(0);
        __builtin_amdgcn_s_barrier();
    }

    // ---- epilogue: C/D layout col = lane&15, row = (lane>>4)*4 + j
    const int rowq = (lane >> 4) * 4;
    const float* bp = bias + (size_t)e * N;

    if (OUT_MODE == 0) {
        unsigned short* Y = (unsigned short*)Cout + (size_t)e * M * N;
#pragma unroll
        for (int n = 0; n < 4; ++n) {
            const int cg = bn0 + wc * 64 + n * 16 + fr;
            const float bb = bp[cg];
#pragma unroll
            for (int m = 0; m < 8; ++m) {
                const int rg0 = bm0 + wr * 128 + m * 16 + rowq;
#pragma unroll
                for (int j = 0; j < 4; ++j) {
                    float v = acc[m][n][j] + bb;
                    v = fmaxf(v, 0.0f);
                    Y[(size_t)(rg0 + j) * N + cg] = f2bf(v);
                }
            }
        }
    } else {
        float* O = (float*)Cout + (size_t)e * M * N;
#pragma unroll
        for (int n = 0; n < 4; ++n) {
            const int cg = bn0 + wc * 64 + n * 16 + fr;
            const float bb = bp[cg];
#pragma unroll
            for (int m = 0; m < 8; ++m) {
                const int rg0 = bm0 + wr * 128 + m * 16 + rowq;
#pragma unroll
                for (int j = 0; j < 4; ++j) {
                    O[(size_t)(rg0 + j) * N + cg] = acc[m][n][j] + bb;
                }
            }
        }
    }
}

extern "C" void kernel_launch(void* const* d_in, const int* in_sizes, int n_in,
                              void* d_out, int out_size, void* d_ws, size_t ws_size,
                              hipStream_t stream) {
    const float* x     = (const float*)d_in[0]; // (E,T,D)
    const float* fc1_w = (const float*)d_in[1]; // (E,D,H)
    const float* fc1_b = (const float*)d_in[2]; // (E,1,H)
    const float* fc2_w = (const float*)d_in[3]; // (E,H,D)
    const float* fc2_b = (const float*)d_in[4]; // (E,1,D)
    float* out = (float*)d_out;

    const size_t n_x  = (size_t)E_ * T_ * D_;
    const size_t n_w1 = (size_t)E_ * D_ * H_;
    const size_t n_w2 = (size_t)E_ * H_ * D_;
    const size_t n_y1 = (size_t)E_ * T_ * H_;

    const size_t need = (n_x + n_w1 + n_w2 + n_y1) * sizeof(unsigned short);
    if (ws_size < need) return;

    unsigned short* xb  = (unsigned short*)d_ws;
    unsigned short* w1t = xb + n_x;    // (E,H,D)
    unsigned short* w2t = w1t + n_w1;  // (E,D,H)
    unsigned short* y1  = w2t + n_w2;  // (E,T,H)

    cvt_x_kernel<<<2048, 256, 0, stream>>>((const float4*)x, (uint2*)xb, (long)(n_x / 4));
    {
        dim3 g(H_ / 64, D_ / 64, E_);
        transpose_cvt_kernel<<<g, 256, 0, stream>>>(fc1_w, w1t, D_, H_);
    }
    {
        dim3 g(D_ / 64, H_ / 64, E_);
        transpose_cvt_kernel<<<g, 256, 0, stream>>>(fc2_w, w2t, H_, D_);
    }
    // GEMM1: y1 = relu(x @ W1 + b1), bf16 out. M=T, N=H, K=D
    {
        dim3 g(H_ / 256, T_ / 256, E_);
        gemm256_kernel<D_, 0><<<g, 512, 0, stream>>>(xb, w1t, fc1_b, (void*)y1, T_, H_);
    }
    // GEMM2: out = y1 @ W2 + b2, f32 out. M=T, N=D, K=H
    {
        dim3 g(D_ / 256, T_ / 256, E_);
        gemm256_kernel<H_, 1><<<g, 512, 0, stream>>>(y1, w2t, fc2_b, (void*)out, T_, D_);
    }
}

// Round 5
// 1159.646 us; speedup vs baseline: 1.0464x; 1.0464x over previous
//
#include <hip/hip_runtime.h>
#include <hip/hip_bf16.h>
#include <stdint.h>

#define E_ 4
#define T_ 4096
#define D_ 2048
#define H_ 8192

typedef __attribute__((ext_vector_type(8))) short bf16x8;
typedef __attribute__((ext_vector_type(4))) float f32x4;
typedef __attribute__((ext_vector_type(4))) unsigned short u16x4;

// round-to-nearest-even f32 -> bf16 bit pattern
__device__ __forceinline__ unsigned short f2bf(float f) {
    unsigned int u = __float_as_uint(f);
    u = u + 0x7fffu + ((u >> 16) & 1u);
    return (unsigned short)(u >> 16);
}

// async global->LDS, 16B per lane. LDS dest is wave-uniform base; HW adds lane*16.
__device__ __forceinline__ void async16(const unsigned short* g, unsigned short* l) {
    auto gp = (const __attribute__((address_space(1))) unsigned int*)g;
    auto lp = (__attribute__((address_space(3))) unsigned int*)l;
    __builtin_amdgcn_global_load_lds(gp, lp, 16 /*bytes*/, 0 /*offset*/, 0 /*aux*/);
}

__device__ __forceinline__ f32x4 mfma16(bf16x8 a, bf16x8 b, f32x4 c) {
    return __builtin_amdgcn_mfma_f32_16x16x32_bf16(a, b, c, 0, 0, 0);
}

// ---------------- x: f32 -> bf16 (vectorized) ----------------
__global__ void cvt_x_kernel(const float4* __restrict__ in, uint2* __restrict__ out, long n4) {
    long i = (long)blockIdx.x * blockDim.x + threadIdx.x;
    long stride = (long)gridDim.x * blockDim.x;
    for (; i < n4; i += stride) {
        float4 v = in[i];
        uint2 o;
        o.x = (unsigned)f2bf(v.x) | ((unsigned)f2bf(v.y) << 16);
        o.y = (unsigned)f2bf(v.z) | ((unsigned)f2bf(v.w) << 16);
        out[i] = o;
    }
}

// ---------------- W (R x C, f32, row-major) -> Wt (C x R, bf16) per expert ----------------
__global__ void transpose_cvt_kernel(const float* __restrict__ W, unsigned short* __restrict__ Wt,
                                     int R, int C) {
    __shared__ float tile[64][65];
    const float* Wp = W + (size_t)blockIdx.z * R * C;
    unsigned short* Wtp = Wt + (size_t)blockIdx.z * R * C;
    const int c0 = blockIdx.x * 64, r0 = blockIdx.y * 64;
    const int tc = threadIdx.x & 63;
    const int tr = threadIdx.x >> 6; // 0..3
#pragma unroll
    for (int i = 0; i < 16; ++i) {
        int r = tr * 16 + i;
        tile[r][tc] = Wp[(size_t)(r0 + r) * C + c0 + tc];
    }
    __syncthreads();
#pragma unroll
    for (int i = 0; i < 16; ++i) {
        int r = tr * 16 + i;
        Wtp[(size_t)(c0 + r) * R + r0 + tc] = f2bf(tile[tc][r]);
    }
}

// ---------------- 256x256 GEMM: C[M][N] = A[M][K] * Bt[N][K]^T (+bias) ----------------
// 8 waves (2M x 4N), per-wave 128x64 output = acc[8][4] of 16x16 frags. BK=64.
// LDS: 2 dbuf x {A,B} x 2 halves x [128][64] bf16 = 128 KiB. XOR swizzle (verified conflict-free).
// K-loop = r3's 2-barrier schedule (best measured). New this round:
//  * L3 supertile remap: within each XCD chunk, bx iterated in groups of GX before advancing
//    by -> B-group L2/L3-resident across the chunk's by-rows; A re-read nx/GX times.
//  * Epilogue LDS-transpose: acc -> [32][260] f32 LDS stripes -> contiguous 512B/1KB row
//    stores (kills write-sector RMW amplification).
template <int K, int OUT_MODE>
__global__ __launch_bounds__(512, 2) void gemm256_kernel(
    const unsigned short* __restrict__ A,   // [E][M][K]
    const unsigned short* __restrict__ Bt,  // [E][N][K]
    const float* __restrict__ bias,         // [E][N]
    void* __restrict__ Cout,                // [E][M][N]
    int M, int N)
{
    constexpr int BK = 64;
    constexpr int NT = K / BK;
    __shared__ __align__(16) unsigned short L[2][2][2][128][64]; // [dbuf][A/B][half][row][kel]

    // ---- XCD chunk + L3 supertile remap ------------------------------------
    // original linear w (bx fastest). xcd = w&7 gets chunk c = w>>3 of cpx blocks.
    // chunk covers CR=cpx/nx consecutive flat-rows fy (fy = e*ny+by). Within chunk:
    // bx-groups of GX iterated outermost-slowest: c -> (g, byl, bxi).
    const int nx = gridDim.x, ny = gridDim.y;
    const int nwg = nx * ny * gridDim.z;
    const int w = (blockIdx.z * ny + blockIdx.y) * nx + blockIdx.x;
    const int cpx = nwg >> 3;
    const int xcd = w & 7;
    const int c = w >> 3;
    const int CR = cpx / nx;                       // by-rows per chunk (8 for our grids)
    const int GX = (nx % 16 == 0) ? 16 : nx;       // bx-group width (16 / nx=8)
    const int g = c / (GX * CR);
    const int r1 = c - g * (GX * CR);
    const int byl = r1 / GX;
    const int bxi = r1 - byl * GX;
    const int fy = xcd * CR + byl;
    const int bx = g * GX + bxi;
    const int e = fy / ny;
    const int by = fy - e * ny;

    const unsigned short* Ae = A + (size_t)e * M * K;
    const unsigned short* Be = Bt + (size_t)e * N * K;
    const int bm0 = by * 256;
    const int bn0 = bx * 256;

    const int tid = threadIdx.x;
    const int lane = tid & 63;
    const int wid = tid >> 6;     // 0..7
    const int wr = wid >> 2;      // 0..1 (M half)
    const int wc = wid & 3;       // 0..3 (N quarter)

    // staging geometry: per call i in 0..1, rows wid*16 + i*8 + (lane>>3)
    const int srow = wid * 16 + (lane >> 3);
    const int skel = 8 * ((lane & 7) ^ (lane >> 3)); // pre-swizzled global k offset

    // fragment-read geometry
    const int fr = lane & 15;
    const int kq = lane >> 4;          // 0..3
    const int ksw = (lane & 7) << 3;   // read-side swizzle (elements)
    const int bh = wc >> 1;            // B half this wave reads
    const int brb = (wc & 1) * 64;     // B row base within half

    f32x4 acc[8][4] = {};

    auto stageA = [&](int t, int h) {
        const int k0 = t * BK;
        const int s = t & 1;
#pragma unroll
        for (int i = 0; i < 2; ++i) {
            async16(Ae + (size_t)(bm0 + h * 128 + srow + i * 8) * K + k0 + skel,
                    &L[s][0][h][wid * 16 + i * 8][0]);
        }
    };
    auto stageB = [&](int t, int h) {
        const int k0 = t * BK;
        const int s = t & 1;
#pragma unroll
        for (int i = 0; i < 2; ++i) {
            async16(Be + (size_t)(bn0 + h * 128 + srow + i * 8) * K + k0 + skel,
                    &L[s][1][h][wid * 16 + i * 8][0]);
        }
    };

    // ---- prologue: stage tiles 0 and 1 (8 loads each; 16 in flight)
    stageB(0, 0); stageB(0, 1); stageA(0, 0); stageA(0, 1);
    stageB(1, 0); stageB(1, 1); stageA(1, 0); stageA(1, 1);

    bf16x8 a[4][2], b[4][2];

    for (int t = 0; t < NT; ++t) {
        const int s = t & 1;

        // ---- tile-t data visible to all waves
        if (t == NT - 1) {
            asm volatile("s_waitcnt vmcnt(0)" ::: "memory");
        } else {
            asm volatile("s_waitcnt vmcnt(8)" ::: "memory");
        }
        __builtin_amdgcn_s_barrier();

        // ---- fragment reads: b (8) + a-lo (8)
#pragma unroll
        for (int n = 0; n < 2; ++n)
#pragma unroll
            for (int kk = 0; kk < 2; ++kk)
                b[n][kk] = *(const bf16x8*)&L[s][1][bh][brb + n * 16 + fr][(kk * 32 + kq * 8) ^ ksw];
#pragma unroll
        for (int m = 0; m < 4; ++m)
#pragma unroll
            for (int kk = 0; kk < 2; ++kk)
                a[m][kk] = *(const bf16x8*)&L[s][0][wr][m * 16 + fr][(kk * 32 + kq * 8) ^ ksw];
#pragma unroll
        for (int n = 2; n < 4; ++n)
#pragma unroll
            for (int kk = 0; kk < 2; ++kk)
                b[n][kk] = *(const bf16x8*)&L[s][1][bh][brb + n * 16 + fr][(kk * 32 + kq * 8) ^ ksw];

        // ---- Q1+Q2: a-lo x all b (32 MFMA)
        __builtin_amdgcn_s_setprio(1);
#pragma unroll
        for (int m = 0; m < 4; ++m)
#pragma unroll
            for (int n = 0; n < 4; ++n)
#pragma unroll
                for (int kk = 0; kk < 2; ++kk)
                    acc[m][n] = mfma16(a[m][kk], b[n][kk], acc[m][n]);
        __builtin_amdgcn_s_setprio(0);

        // ---- a-hi reads (reuse a regs; WAR vs Q1/Q2 handled by compiler dep tracking)
#pragma unroll
        for (int m = 0; m < 4; ++m)
#pragma unroll
            for (int kk = 0; kk < 2; ++kk)
                a[m][kk] = *(const bf16x8*)&L[s][0][wr][(m + 4) * 16 + fr][(kk * 32 + kq * 8) ^ ksw];

        // ---- all slot-s reads landed in registers, across all waves -> slot dead
        asm volatile("s_waitcnt lgkmcnt(0)" ::: "memory");
        __builtin_amdgcn_sched_barrier(0);
        __builtin_amdgcn_s_barrier();

        // ---- stage tile t+2 into the dead slot (8 gloads), pinned before Q3/Q4
        if (t + 2 < NT) {
            stageB(t + 2, 0); stageB(t + 2, 1);
            stageA(t + 2, 0); stageA(t + 2, 1);
        }
        __builtin_amdgcn_sched_barrier(0);

        // ---- Q3+Q4: a-hi x all b (32 MFMA) — covers stage issue + HBM latency
        __builtin_amdgcn_s_setprio(1);
#pragma unroll
        for (int m = 0; m < 4; ++m)
#pragma unroll
            for (int n = 0; n < 4; ++n)
#pragma unroll
                for (int kk = 0; kk < 2; ++kk)
                    acc[m + 4][n] = mfma16(a[m][kk], b[n][kk], acc[m + 4][n]);
        __builtin_amdgcn_s_setprio(0);
    }

    // ---- epilogue: LDS-transpose to contiguous row stores ----------------------
    // acc frag layout: col = lane&15 (fr), row = (lane>>4)*4 + j.
    // 8 stripes of 32 rows. Stripe s written by the 4 waves with wr==s>>2
    // (frags m in {2*(s&3), 2*(s&3)+1}), then all 8 waves read 4 full rows each.
    constexpr int ST = 260;                     // f32 stride: 4*260 B; 2-way bank residue
    float* S = (float*)&L[0][0][0][0][0];       // 32*260*4 = 33280 B, fits in dead LDS
    const int rowq = (lane >> 4) * 4;
    const float* bp = bias + (size_t)e * N;
    const float4 bb4 = *(const float4*)(bp + bn0 + lane * 4); // this lane's 4 output cols

    unsigned short* Y = (unsigned short*)Cout + (size_t)e * M * N;
    float* O = (float*)Cout + (size_t)e * M * N;

#pragma unroll
    for (int s = 0; s < 8; ++s) {
        __syncthreads();  // LDS free (K-loop done / previous stripe readout done)
        if (wr == (s >> 2)) {
            const int sl = s & 3;
#pragma unroll
            for (int mm = 0; mm < 2; ++mm) {
#pragma unroll
                for (int n = 0; n < 4; ++n) {
#pragma unroll
                    for (int j = 0; j < 4; ++j) {
                        S[(mm * 16 + rowq + j) * ST + wc * 64 + n * 16 + fr] =
                            acc[2 * sl + mm][n][j];
                    }
                }
            }
        }
        __syncthreads();
#pragma unroll
        for (int rr = 0; rr < 4; ++rr) {
            const int rl = wid * 4 + rr;             // row within stripe
            const int rg = bm0 + s * 32 + rl;        // global row
            f32x4 v = *(const f32x4*)&S[rl * ST + lane * 4];
            v[0] += bb4.x; v[1] += bb4.y; v[2] += bb4.z; v[3] += bb4.w;
            if (OUT_MODE == 0) {
                u16x4 o;
                o[0] = f2bf(fmaxf(v[0], 0.0f));
                o[1] = f2bf(fmaxf(v[1], 0.0f));
                o[2] = f2bf(fmaxf(v[2], 0.0f));
                o[3] = f2bf(fmaxf(v[3], 0.0f));
                *(u16x4*)(Y + (size_t)rg * N + bn0 + lane * 4) = o;
            } else {
                *(f32x4*)(O + (size_t)rg * N + bn0 + lane * 4) = v;
            }
        }
    }
}

extern "C" void kernel_launch(void* const* d_in, const int* in_sizes, int n_in,
                              void* d_out, int out_size, void* d_ws, size_t ws_size,
                              hipStream_t stream) {
    const float* x     = (const float*)d_in[0]; // (E,T,D)
    const float* fc1_w = (const float*)d_in[1]; // (E,D,H)
    const float* fc1_b = (const float*)d_in[2]; // (E,1,H)
    const float* fc2_w = (const float*)d_in[3]; // (E,H,D)
    const float* fc2_b = (const float*)d_in[4]; // (E,1,D)
    float* out = (float*)d_out;

    const size_t n_x  = (size_t)E_ * T_ * D_;
    const size_t n_w1 = (size_t)E_ * D_ * H_;
    const size_t n_w2 = (size_t)E_ * H_ * D_;
    const size_t n_y1 = (size_t)E_ * T_ * H_;

    const size_t need = (n_x + n_w1 + n_w2 + n_y1) * sizeof(unsigned short);
    if (ws_size < need) return;

    unsigned short* xb  = (unsigned short*)d_ws;
    unsigned short* w1t = xb + n_x;    // (E,H,D)
    unsigned short* w2t = w1t + n_w1;  // (E,D,H)
    unsigned short* y1  = w2t + n_w2;  // (E,T,H)

    cvt_x_kernel<<<2048, 256, 0, stream>>>((const float4*)x, (uint2*)xb, (long)(n_x / 4));
    {
        dim3 g(H_ / 64, D_ / 64, E_);
        transpose_cvt_kernel<<<g, 256, 0, stream>>>(fc1_w, w1t, D_, H_);
    }
    {
        dim3 g(D_ / 64, H_ / 64, E_);
        transpose_cvt_kernel<<<g, 256, 0, stream>>>(fc2_w, w2t, H_, D_);
    }
    // GEMM1: y1 = relu(x @ W1 + b1), bf16 out. M=T, N=H, K=D
    {
        dim3 g(H_ / 256, T_ / 256, E_);
        gemm256_kernel<D_, 0><<<g, 512, 0, stream>>>(xb, w1t, fc1_b, (void*)y1, T_, H_);
    }
    // GEMM2: out = y1 @ W2 + b2, f32 out. M=T, N=D, K=H
    {
        dim3 g(D_ / 256, T_ / 256, E_);
        gemm256_kernel<H_, 1><<<g, 512, 0, stream>>>(y1, w2t, fc2_b, (void*)out, T_, D_);
    }
}